// Round 8
// baseline (366.849 us; speedup 1.0000x reference)
//
#include <hip/hip_runtime.h>

// Problem constants
#define NSPLIT  100
#define MTREE   20
#define MAXLEAF 64
#define EMB     32
#define NTREES  2000
#define BATCH   4096
#define OUTW    (NSPLIT*EMB)          // 3200

#define THREADS 512
#define CHUNKS  16                    // batch-chunks per split
#define BPC     (BATCH/CHUNKS)        // 256 batches per block
#define GROUPS  (THREADS/4)           // 128 groups of 4 lanes; 2 batches each
#define TAB_F4  (MTREE*MAXLEAF*8)     // 10240 float4 per split table
#define PASS_F4 (TAB_F4/2)            // 5120 float4 staged per pass (10 trees)

// v8: bf16 gather with REAL co-residency.
//  - 40 KiB STATIC LDS (10 trees/pass, 2 passes) + 512-thread blocks +
//    __launch_bounds__(512,6): 3 blocks x 8 waves = 24 waves/CU. v3/v4/v7
//    (64-160 KiB dynamic LDS) all pinned at ~31% occupancy & ~40us -- the
//    dynamic-LDS blocks never co-scheduled, so stage->barrier->gather chains
//    ran serially with 4 waves/SIMD. Static 40 KiB removes that failure mode.
//  - bf16 rows (64B): one ds_read_b128 wave-instr = 16 row-gathers.
//  - VGPR discipline (v6 lesson): <=4 uint4 in flight, per-pass leaf regs,
//    2-deep staging unroll; live ~70 under the ~84 cap.
__device__ __forceinline__ unsigned int pk_bf16(float a, float b) {
    unsigned int r;
    asm("v_cvt_pk_bf16_f32 %0, %1, %2" : "=v"(r) : "v"(a), "v"(b));
    return r;
}

__global__ __launch_bounds__(THREADS, 6) void leaf2emb_v8(
    const int* __restrict__ leaves,     // [BATCH, NTREES]
    const float* __restrict__ embed,    // [NSPLIT, MTREE*MAXLEAF, EMB]
    float* __restrict__ out)            // [BATCH, OUTW]
{
    __shared__ unsigned int tabw[10 * MAXLEAF * 16];   // 40960 B, row = 64 B

    // XCD-chunked swizzle: 1600 = 8 x 200 -> a split's 16 chunk-blocks stay
    // on one XCD; its L2 holds the ~2-3 tables being staged.
    const int bid = blockIdx.x;
    const int wkr = (bid & 7) * (NSPLIT * CHUNKS / 8) + (bid >> 3);
    const int s     = wkr >> 4;
    const int chunk = wkr & 15;

    const int tid = threadIdx.x;
    const int l   = tid & 3;            // lane-in-group: dims [8l, 8l+8)
    const int g   = tid >> 2;           // group id

    const float4* emb4 = (const float4*)embed + (size_t)s * TAB_F4;
    uint2* tw = (uint2*)tabw;

    const int bA = chunk * BPC + g;
    const int bB = bA + GROUPS;
    const int* lvA = leaves + (size_t)bA * NTREES + s * MTREE;
    const int* lvB = leaves + (size_t)bB * NTREES + s * MTREE;

    const char* tb = (const char*)tabw + l * 16;
    float4 aA0 = {0,0,0,0}, aA1 = {0,0,0,0};
    float4 aB0 = {0,0,0,0}, aB1 = {0,0,0,0};

#define STAGE(P) { \
        _Pragma("unroll 2") \
        for (int k = 0; k < 10; ++k) { \
            float4 v = emb4[(P)*PASS_F4 + tid + k*512]; \
            tw[tid + k*512] = make_uint2(pk_bf16(v.x, v.y), pk_bf16(v.z, v.w)); \
        } }

#define RD(T, LEAF) (*(const uint4*)(tb + (T)*4096 + ((LEAF) << 6)))
#define UNACC(P0, P1, V) { \
    P0.x += __uint_as_float((V).x << 16); P0.y += __uint_as_float((V).x & 0xffff0000u); \
    P0.z += __uint_as_float((V).y << 16); P0.w += __uint_as_float((V).y & 0xffff0000u); \
    P1.x += __uint_as_float((V).z << 16); P1.y += __uint_as_float((V).z & 0xffff0000u); \
    P1.z += __uint_as_float((V).w << 16); P1.w += __uint_as_float((V).w & 0xffff0000u); }

    // 10 trees for one batch from the staged pass: 4+4+2 reads in flight.
#define GATHER10(P0, P1, L0, L1, LH) { \
        uint4 v0 = RD(0, (L0).x), v1 = RD(1, (L0).y), \
              v2 = RD(2, (L0).z), v3 = RD(3, (L0).w); \
        UNACC(P0, P1, v0) UNACC(P0, P1, v1) UNACC(P0, P1, v2) UNACC(P0, P1, v3) \
        v0 = RD(4, (L1).x); v1 = RD(5, (L1).y); \
        v2 = RD(6, (L1).z); v3 = RD(7, (L1).w); \
        UNACC(P0, P1, v0) UNACC(P0, P1, v1) UNACC(P0, P1, v2) UNACC(P0, P1, v3) \
        v0 = RD(8, (LH).x); v1 = RD(9, (LH).y); \
        UNACC(P0, P1, v0) UNACC(P0, P1, v1) }

    // ---- pass 0: trees 0..9 ----
    STAGE(0)
    int4 LA0 = *(const int4*)(lvA);     int4 LB0 = *(const int4*)(lvB);
    int4 LA1 = *(const int4*)(lvA + 4); int4 LB1 = *(const int4*)(lvB + 4);
    int2 LAh = *(const int2*)(lvA + 8); int2 LBh = *(const int2*)(lvB + 8);
    __syncthreads();
    GATHER10(aA0, aA1, LA0, LA1, LAh)
    GATHER10(aB0, aB1, LB0, LB1, LBh)
    // pass-1 leaves issued here: latency hides under barrier + stage(1)
    LAh = *(const int2*)(lvA + 10); LBh = *(const int2*)(lvB + 10);
    LA0 = *(const int4*)(lvA + 12); LB0 = *(const int4*)(lvB + 12);
    LA1 = *(const int4*)(lvA + 16); LB1 = *(const int4*)(lvB + 16);
    __syncthreads();                    // gathers done -> safe to re-stage

    // ---- pass 1: trees 10..19 (tree order within pass: 10,11 | 12..15 | 16..19) ----
    STAGE(1)
    __syncthreads();
    {   // trees 10,11 live at pass-rows 0,1; 12..15 at 2..5; 16..19 at 6..9
        uint4 v0 = RD(0, LAh.x), v1 = RD(1, LAh.y);
        UNACC(aA0, aA1, v0) UNACC(aA0, aA1, v1)
        v0 = RD(2, LA0.x); v1 = RD(3, LA0.y);
        uint4 v2 = RD(4, LA0.z), v3 = RD(5, LA0.w);
        UNACC(aA0, aA1, v0) UNACC(aA0, aA1, v1) UNACC(aA0, aA1, v2) UNACC(aA0, aA1, v3)
        v0 = RD(6, LA1.x); v1 = RD(7, LA1.y); v2 = RD(8, LA1.z); v3 = RD(9, LA1.w);
        UNACC(aA0, aA1, v0) UNACC(aA0, aA1, v1) UNACC(aA0, aA1, v2) UNACC(aA0, aA1, v3)

        v0 = RD(0, LBh.x); v1 = RD(1, LBh.y);
        UNACC(aB0, aB1, v0) UNACC(aB0, aB1, v1)
        v0 = RD(2, LB0.x); v1 = RD(3, LB0.y); v2 = RD(4, LB0.z); v3 = RD(5, LB0.w);
        UNACC(aB0, aB1, v0) UNACC(aB0, aB1, v1) UNACC(aB0, aB1, v2) UNACC(aB0, aB1, v3)
        v0 = RD(6, LB1.x); v1 = RD(7, LB1.y); v2 = RD(8, LB1.z); v3 = RD(9, LB1.w);
        UNACC(aB0, aB1, v0) UNACC(aB0, aB1, v1) UNACC(aB0, aB1, v2) UNACC(aB0, aB1, v3)
    }

#undef STAGE
#undef RD
#undef UNACC
#undef GATHER10

    // group's 4 lanes write 2 float4 each -> contiguous 128B per (b, s)
    float* oA = out + (size_t)bA * OUTW + s * EMB + l * 8;
    float* oB = out + (size_t)bB * OUTW + s * EMB + l * 8;
    *(float4*)(oA)     = aA0;
    *(float4*)(oA + 4) = aA1;
    *(float4*)(oB)     = aB0;
    *(float4*)(oB + 4) = aB1;
}

extern "C" void kernel_launch(void* const* d_in, const int* in_sizes, int n_in,
                              void* d_out, int out_size, void* d_ws, size_t ws_size,
                              hipStream_t stream) {
    const int* leaves  = (const int*)d_in[0];
    const float* embed = (const float*)d_in[1];
    float* out         = (float*)d_out;

    dim3 grid(NSPLIT * CHUNKS);   // 1600
    dim3 block(THREADS);          // 512
    leaf2emb_v8<<<grid, block, 0, stream>>>(leaves, embed, out);
}

// Round 9
// 166.378 us; speedup vs baseline: 2.2049x; 2.2049x over previous
//
#include <hip/hip_runtime.h>

// Problem constants
#define NSPLIT  100
#define MTREE   20
#define MAXLEAF 64
#define EMB     32
#define NTREES  2000
#define BATCH   4096
#define OUTW    (NSPLIT*EMB)          // 3200

#define THREADS 512
#define CHUNKS  32                    // batch-chunks per split
#define BPC     (BATCH/CHUNKS)        // 128 batches per block (1 per 4-lane group)
#define NBLK    (NSPLIT*CHUNKS)       // 3200
#define TAB_F4  (MTREE*MAXLEAF*8)     // 10240 float4 per split table
#define PASS_F4 (TAB_F4/2)            // 5120 float4 per 10-tree pass

// v9 = v8's co-residency (static 40 KiB LDS + 512-thread blocks: proven
// 60% occupancy) + v7's VGPR discipline (proven 52 regs, no spill).
//  - __launch_bounds__(512,8) -> VGPR cap 64, a REAL occupancy tier
//    (<=64 -> 8 waves/SIMD). v8's (512,6) demanded a tier that doesn't
//    exist -> compiler crushed to 40 VGPR -> 874 MB scratch writes.
//  - 1 batch per 4-lane group keeps live state ~50 regs: acc 8, leaves 10,
//    <=4 gather uint4 in flight, staging unroll 2.
//  - bf16 rows (64B): one ds_read_b128 wave-instr = 16 row-gathers; whole
//    chip port floor ~10us, VALU unpack ~7us, overlapped via 4 blocks/CU.
__device__ __forceinline__ unsigned int pk_bf16(float a, float b) {
    unsigned int r;
    asm("v_cvt_pk_bf16_f32 %0, %1, %2" : "=v"(r) : "v"(a), "v"(b));
    return r;
}

__global__ __launch_bounds__(THREADS, 8) void leaf2emb_v9(
    const int* __restrict__ leaves,     // [BATCH, NTREES]
    const float* __restrict__ embed,    // [NSPLIT, MTREE*MAXLEAF, EMB]
    float* __restrict__ out)            // [BATCH, OUTW]
{
    __shared__ unsigned int tabw[10 * MAXLEAF * 16];   // 40960 B, row = 64 B

    // XCD-chunked swizzle: 3200 = 8 x 400 -> a split's 32 chunk-blocks stay
    // on one XCD; its L2 holds the ~3 tables being staged there.
    const int bid = blockIdx.x;
    const int wkr = (bid & 7) * (NBLK / 8) + (bid >> 3);
    const int s     = wkr >> 5;
    const int chunk = wkr & 31;

    const int tid = threadIdx.x;
    const int l   = tid & 3;            // lane-in-group: dims [8l, 8l+8)
    const int g   = tid >> 2;           // group id = batch slot (128 groups)

    const float4* emb4 = (const float4*)embed + (size_t)s * TAB_F4;
    uint2* tw = (uint2*)tabw;

    const int b = chunk * BPC + g;
    const int* lv = leaves + (size_t)b * NTREES + s * MTREE;

    const char* tb = (const char*)tabw + l * 16;
    float4 a0 = {0,0,0,0}, a1 = {0,0,0,0};   // dims [8l..8l+4), [8l+4..8l+8)

#define STAGE(P) { \
        _Pragma("unroll 2") \
        for (int k = 0; k < 10; ++k) { \
            float4 v = emb4[(P)*PASS_F4 + tid + k*512]; \
            tw[tid + k*512] = make_uint2(pk_bf16(v.x, v.y), pk_bf16(v.z, v.w)); \
        } }

#define RD(T, LEAF) (*(const uint4*)(tb + (T)*4096 + ((LEAF) << 6)))
#define UNACC(V) { \
    a0.x += __uint_as_float((V).x << 16); a0.y += __uint_as_float((V).x & 0xffff0000u); \
    a0.z += __uint_as_float((V).y << 16); a0.w += __uint_as_float((V).y & 0xffff0000u); \
    a1.x += __uint_as_float((V).z << 16); a1.y += __uint_as_float((V).z & 0xffff0000u); \
    a1.z += __uint_as_float((V).w << 16); a1.w += __uint_as_float((V).w & 0xffff0000u); }

    // 10 trees from the staged pass: 4+4+2 reads in flight (<=4 uint4 live).
#define GATHER10(L0, L1, LH) { \
        uint4 v0 = RD(0, (L0).x), v1 = RD(1, (L0).y), \
              v2 = RD(2, (L0).z), v3 = RD(3, (L0).w); \
        UNACC(v0) UNACC(v1) UNACC(v2) UNACC(v3) \
        v0 = RD(4, (L1).x); v1 = RD(5, (L1).y); \
        v2 = RD(6, (L1).z); v3 = RD(7, (L1).w); \
        UNACC(v0) UNACC(v1) UNACC(v2) UNACC(v3) \
        v0 = RD(8, (LH).x); v1 = RD(9, (LH).y); \
        UNACC(v0) UNACC(v1) }

    // ---- pass 0: trees 0..9 staged at rows 0..9 ----
    STAGE(0)
    int4 L0 = *(const int4*)(lv);       // trees 0..3
    int4 L1 = *(const int4*)(lv + 4);   // trees 4..7
    int2 Lh = *(const int2*)(lv + 8);   // trees 8,9
    __syncthreads();
    GATHER10(L0, L1, Lh)
    // pass-1 leaves: issued here so latency hides under barrier + STAGE(1)
    Lh = *(const int2*)(lv + 10);       // trees 10,11 -> rows 0,1
    L0 = *(const int4*)(lv + 12);       // trees 12..15 -> rows 2..5
    L1 = *(const int4*)(lv + 16);       // trees 16..19 -> rows 6..9
    __syncthreads();                    // all gathers done -> safe to re-stage

    // ---- pass 1: trees 10..19 staged at rows 0..9 ----
    STAGE(1)
    __syncthreads();
    {
        uint4 v0 = RD(0, Lh.x), v1 = RD(1, Lh.y);
        UNACC(v0) UNACC(v1)
        v0 = RD(2, L0.x); v1 = RD(3, L0.y);
        uint4 v2 = RD(4, L0.z), v3 = RD(5, L0.w);
        UNACC(v0) UNACC(v1) UNACC(v2) UNACC(v3)
        v0 = RD(6, L1.x); v1 = RD(7, L1.y); v2 = RD(8, L1.z); v3 = RD(9, L1.w);
        UNACC(v0) UNACC(v1) UNACC(v2) UNACC(v3)
    }

#undef STAGE
#undef RD
#undef UNACC
#undef GATHER10

    // group's 4 lanes write 2 float4 each -> contiguous 128B per (b, s)
    float* ob = out + (size_t)b * OUTW + s * EMB + l * 8;
    *(float4*)(ob)     = a0;
    *(float4*)(ob + 4) = a1;
}

extern "C" void kernel_launch(void* const* d_in, const int* in_sizes, int n_in,
                              void* d_out, int out_size, void* d_ws, size_t ws_size,
                              hipStream_t stream) {
    const int* leaves  = (const int*)d_in[0];
    const float* embed = (const float*)d_in[1];
    float* out         = (float*)d_out;

    dim3 grid(NBLK);        // 3200
    dim3 block(THREADS);    // 512
    leaf2emb_v9<<<grid, block, 0, stream>>>(leaves, embed, out);
}

// Round 10
// 50.402 us; speedup vs baseline: 7.2784x; 3.3010x over previous
//
#include <hip/hip_runtime.h>

// Problem constants
#define NSPLIT  100
#define MTREE   20
#define MAXLEAF 64
#define EMB     32
#define NTREES  2000
#define BATCH   4096
#define OUTW    (NSPLIT*EMB)          // 3200

#define THREADS 512
#define CHUNKS  32                    // batch-chunks per split
#define BPC     (BATCH/CHUNKS)        // 128 batches per block (1 per 4-lane group)
#define NBLK    (NSPLIT*CHUNKS)       // 3200
#define TAB_F4  (MTREE*MAXLEAF*8)     // 10240 float4 per split table
#define PASS_F4 (TAB_F4/2)            // 5120 float4 per 10-tree pass

// v10 = v9 with the __launch_bounds__ second arg fixed.
// Empirically on this hipcc the 2nd arg acts as MIN BLOCKS PER CU:
//   v6 (512,4)->VGPR 64   v7 (1024,2)->64   v8 (512,6)->40   v9 (512,8)->32
//   (cap = 512 / (arg2 * block_waves / 4)). v9 asked for 64 waves/CU ->
//   cap 32 -> ~20 spilled regs -> 511 MB scratch writes. Occupancy itself
//   hit 82%: static-LDS co-residency is PROVEN; only the reg cap was wrong.
// (512,4): 4 blocks x 8 waves = 32 waves/CU, VGPR cap 64; live state ~50.
__device__ __forceinline__ unsigned int pk_bf16(float a, float b) {
    unsigned int r;
    asm("v_cvt_pk_bf16_f32 %0, %1, %2" : "=v"(r) : "v"(a), "v"(b));
    return r;
}

__global__ __launch_bounds__(THREADS, 4) void leaf2emb_v10(
    const int* __restrict__ leaves,     // [BATCH, NTREES]
    const float* __restrict__ embed,    // [NSPLIT, MTREE*MAXLEAF, EMB]
    float* __restrict__ out)            // [BATCH, OUTW]
{
    __shared__ unsigned int tabw[10 * MAXLEAF * 16];   // 40960 B, row = 64 B

    // XCD-chunked swizzle: 3200 = 8 x 400 -> a split's 32 chunk-blocks stay
    // on one XCD; its L2 holds the ~3 tables being staged there.
    const int bid = blockIdx.x;
    const int wkr = (bid & 7) * (NBLK / 8) + (bid >> 3);
    const int s     = wkr >> 5;
    const int chunk = wkr & 31;

    const int tid = threadIdx.x;
    const int l   = tid & 3;            // lane-in-group: dims [8l, 8l+8)
    const int g   = tid >> 2;           // group id = batch slot (128 groups)

    const float4* emb4 = (const float4*)embed + (size_t)s * TAB_F4;
    uint2* tw = (uint2*)tabw;

    const int b = chunk * BPC + g;
    const int* lv = leaves + (size_t)b * NTREES + s * MTREE;

    const char* tb = (const char*)tabw + l * 16;
    float4 a0 = {0,0,0,0}, a1 = {0,0,0,0};   // dims [8l..8l+4), [8l+4..8l+8)

#define STAGE(P) { \
        _Pragma("unroll 2") \
        for (int k = 0; k < 10; ++k) { \
            float4 v = emb4[(P)*PASS_F4 + tid + k*512]; \
            tw[tid + k*512] = make_uint2(pk_bf16(v.x, v.y), pk_bf16(v.z, v.w)); \
        } }

#define RD(T, LEAF) (*(const uint4*)(tb + (T)*4096 + ((LEAF) << 6)))
#define UNACC(V) { \
    a0.x += __uint_as_float((V).x << 16); a0.y += __uint_as_float((V).x & 0xffff0000u); \
    a0.z += __uint_as_float((V).y << 16); a0.w += __uint_as_float((V).y & 0xffff0000u); \
    a1.x += __uint_as_float((V).z << 16); a1.y += __uint_as_float((V).z & 0xffff0000u); \
    a1.z += __uint_as_float((V).w << 16); a1.w += __uint_as_float((V).w & 0xffff0000u); }

    // 10 trees from the staged pass: 4+4+2 reads in flight (<=4 uint4 live).
#define GATHER10(L0, L1, LH) { \
        uint4 v0 = RD(0, (L0).x), v1 = RD(1, (L0).y), \
              v2 = RD(2, (L0).z), v3 = RD(3, (L0).w); \
        UNACC(v0) UNACC(v1) UNACC(v2) UNACC(v3) \
        v0 = RD(4, (L1).x); v1 = RD(5, (L1).y); \
        v2 = RD(6, (L1).z); v3 = RD(7, (L1).w); \
        UNACC(v0) UNACC(v1) UNACC(v2) UNACC(v3) \
        v0 = RD(8, (LH).x); v1 = RD(9, (LH).y); \
        UNACC(v0) UNACC(v1) }

    // ---- pass 0: trees 0..9 staged at rows 0..9 ----
    STAGE(0)
    int4 L0 = *(const int4*)(lv);       // trees 0..3
    int4 L1 = *(const int4*)(lv + 4);   // trees 4..7
    int2 Lh = *(const int2*)(lv + 8);   // trees 8,9
    __syncthreads();
    GATHER10(L0, L1, Lh)
    // pass-1 leaves: issued here so latency hides under barrier + STAGE(1)
    Lh = *(const int2*)(lv + 10);       // trees 10,11 -> rows 0,1
    L0 = *(const int4*)(lv + 12);       // trees 12..15 -> rows 2..5
    L1 = *(const int4*)(lv + 16);       // trees 16..19 -> rows 6..9
    __syncthreads();                    // all gathers done -> safe to re-stage

    // ---- pass 1: trees 10..19 staged at rows 0..9 ----
    STAGE(1)
    __syncthreads();
    {
        uint4 v0 = RD(0, Lh.x), v1 = RD(1, Lh.y);
        UNACC(v0) UNACC(v1)
        v0 = RD(2, L0.x); v1 = RD(3, L0.y);
        uint4 v2 = RD(4, L0.z), v3 = RD(5, L0.w);
        UNACC(v0) UNACC(v1) UNACC(v2) UNACC(v3)
        v0 = RD(6, L1.x); v1 = RD(7, L1.y); v2 = RD(8, L1.z); v3 = RD(9, L1.w);
        UNACC(v0) UNACC(v1) UNACC(v2) UNACC(v3)
    }

#undef STAGE
#undef RD
#undef UNACC
#undef GATHER10

    // group's 4 lanes write 2 float4 each -> contiguous 128B per (b, s)
    float* ob = out + (size_t)b * OUTW + s * EMB + l * 8;
    *(float4*)(ob)     = a0;
    *(float4*)(ob + 4) = a1;
}

extern "C" void kernel_launch(void* const* d_in, const int* in_sizes, int n_in,
                              void* d_out, int out_size, void* d_ws, size_t ws_size,
                              hipStream_t stream) {
    const int* leaves  = (const int*)d_in[0];
    const float* embed = (const float*)d_in[1];
    float* out         = (float*)d_out;

    dim3 grid(NBLK);        // 3200
    dim3 block(THREADS);    // 512
    leaf2emb_v10<<<grid, block, 0, stream>>>(leaves, embed, out);
}

// Round 11
// 45.188 us; speedup vs baseline: 8.1183x; 1.1154x over previous
//
#include <hip/hip_runtime.h>

// Problem constants
#define NSPLIT  100
#define MTREE   20
#define MAXLEAF 64
#define EMB     32
#define NTREES  2000
#define BATCH   4096
#define OUTW    (NSPLIT*EMB)            // 3200
#define TAB_ROWS (NSPLIT*MTREE*MAXLEAF) // 128000 rows of 32
#define TAB_F4   (TAB_ROWS*8)           // 1,024,000 float4 in f32 table
#define WS_BYTES ((size_t)TAB_ROWS*64)  // 8,192,000 B bf16 table in d_ws

#define THREADS 256
#define CHUNKS  32                      // batch-chunks per split
#define BPC     (BATCH/CHUNKS)          // 128 batches per block
#define NBLK    (NSPLIT*CHUNKS)         // 3200

// v11: abandon per-block LDS staging (family bracketed at ~40us over rounds
// 1-10: every block paid a 16-32x-redundant table-stage + barriers). Instead:
//   kernel 1: convert the 16.4 MB f32 table to bf16 ONCE into d_ws (8.2 MB).
//   kernel 2: gather rows straight from L2. bf16 row = 64 B = one 4-lane
//     group's uint4 load -> a wave-instr covers 16 random rows at half the
//     cache-line cost of v1's f32 (which ran 51us with 2 lines/row).
//   No LDS, no barriers, no staging redundancy; blocks co-schedule freely.
//   XCD-chunked swizzle: each XCD works ~12 splits -> ~1 MB bf16 slice,
//   L2-resident; leaves/out are pure streams.
__device__ __forceinline__ unsigned int pk_bf16(float a, float b) {
    unsigned int r;
    asm("v_cvt_pk_bf16_f32 %0, %1, %2" : "=v"(r) : "v"(a), "v"(b));
    return r;
}

// ---- kernel 1: f32 table -> bf16 table (row-major layout preserved) ----
__global__ __launch_bounds__(256) void cvt_tab(
    const float4* __restrict__ src, uint2* __restrict__ dst)
{
    const int i0 = blockIdx.x * 1024 + threadIdx.x;
#pragma unroll
    for (int k = 0; k < 4; ++k) {
        const int i = i0 + k * 256;          // 1000 blocks x 1024 = exact
        const float4 v = src[i];
        dst[i] = make_uint2(pk_bf16(v.x, v.y), pk_bf16(v.z, v.w));
    }
}

// ---- kernel 2: gather-sum from bf16 table in L2 ----
__global__ __launch_bounds__(THREADS) void leaf2emb_v11(
    const int* __restrict__ leaves,     // [BATCH, NTREES]
    const char* __restrict__ tab,       // bf16 table, row = 64 B
    float* __restrict__ out)            // [BATCH, OUTW]
{
    // XCD-chunked swizzle: 3200 = 8 x 400 -> XCD x owns ~12.5 consecutive
    // splits; its bf16 table slice (~1 MB) stays L2-resident.
    const int bid = blockIdx.x;
    const int wkr = (bid & 7) * (NBLK / 8) + (bid >> 3);
    const int s     = wkr >> 5;
    const int chunk = wkr & 31;

    const int tid = threadIdx.x;
    const int l   = tid & 3;            // lane-in-group: dims [8l, 8l+8)
    const int g   = tid >> 2;           // group id (64 groups, 2 batches each)

    const char* rb = tab + (size_t)s * (MTREE * MAXLEAF * 64) + l * 16;

    const int bA = chunk * BPC + g;
    const int bB = bA + 64;
    const int4* lvA = (const int4*)(leaves + (size_t)bA * NTREES + s * MTREE);
    const int4* lvB = (const int4*)(leaves + (size_t)bB * NTREES + s * MTREE);

    // Both batches' leaves issued up front: 10 independent 16B loads.
    const int4 A0 = lvA[0], A1 = lvA[1], A2 = lvA[2], A3 = lvA[3], A4 = lvA[4];
    const int4 B0 = lvB[0], B1 = lvB[1], B2 = lvB[2], B3 = lvB[3], B4 = lvB[4];

#define RD(T, LEAF) (*(const uint4*)(rb + (T) * 4096 + ((LEAF) << 6)))
#define UNACC(P0, P1, V) { \
    P0.x += __uint_as_float((V).x << 16); P0.y += __uint_as_float((V).x & 0xffff0000u); \
    P0.z += __uint_as_float((V).y << 16); P0.w += __uint_as_float((V).y & 0xffff0000u); \
    P1.x += __uint_as_float((V).z << 16); P1.y += __uint_as_float((V).z & 0xffff0000u); \
    P1.z += __uint_as_float((V).w << 16); P1.w += __uint_as_float((V).w & 0xffff0000u); }

    // 20 gathers per batch, 4 uint4 in flight per quartet.
#define GATHER20(P0, P1, L0, L1, L2, L3, L4) { \
    uint4 v0 = RD(0,(L0).x),  v1 = RD(1,(L0).y),  v2 = RD(2,(L0).z),  v3 = RD(3,(L0).w); \
    UNACC(P0,P1,v0) UNACC(P0,P1,v1) UNACC(P0,P1,v2) UNACC(P0,P1,v3) \
    v0 = RD(4,(L1).x);  v1 = RD(5,(L1).y);  v2 = RD(6,(L1).z);  v3 = RD(7,(L1).w); \
    UNACC(P0,P1,v0) UNACC(P0,P1,v1) UNACC(P0,P1,v2) UNACC(P0,P1,v3) \
    v0 = RD(8,(L2).x);  v1 = RD(9,(L2).y);  v2 = RD(10,(L2).z); v3 = RD(11,(L2).w); \
    UNACC(P0,P1,v0) UNACC(P0,P1,v1) UNACC(P0,P1,v2) UNACC(P0,P1,v3) \
    v0 = RD(12,(L3).x); v1 = RD(13,(L3).y); v2 = RD(14,(L3).z); v3 = RD(15,(L3).w); \
    UNACC(P0,P1,v0) UNACC(P0,P1,v1) UNACC(P0,P1,v2) UNACC(P0,P1,v3) \
    v0 = RD(16,(L4).x); v1 = RD(17,(L4).y); v2 = RD(18,(L4).z); v3 = RD(19,(L4).w); \
    UNACC(P0,P1,v0) UNACC(P0,P1,v1) UNACC(P0,P1,v2) UNACC(P0,P1,v3) }

    float4 a0 = {0,0,0,0}, a1 = {0,0,0,0};
    GATHER20(a0, a1, A0, A1, A2, A3, A4)
    float* oA = out + (size_t)bA * OUTW + s * EMB + l * 8;
    *(float4*)(oA)     = a0;
    *(float4*)(oA + 4) = a1;

    float4 c0 = {0,0,0,0}, c1 = {0,0,0,0};
    GATHER20(c0, c1, B0, B1, B2, B3, B4)
    float* oB = out + (size_t)bB * OUTW + s * EMB + l * 8;
    *(float4*)(oB)     = c0;
    *(float4*)(oB + 4) = c1;

#undef RD
#undef UNACC
#undef GATHER20
}

extern "C" void kernel_launch(void* const* d_in, const int* in_sizes, int n_in,
                              void* d_out, int out_size, void* d_ws, size_t ws_size,
                              hipStream_t stream) {
    const int* leaves  = (const int*)d_in[0];
    const float* embed = (const float*)d_in[1];
    float* out         = (float*)d_out;

    // d_ws: 8.2 MB bf16 table (rewritten fully every call -> deterministic).
    cvt_tab<<<dim3(TAB_F4 / 1024), dim3(256), 0, stream>>>(
        (const float4*)embed, (uint2*)d_ws);

    leaf2emb_v11<<<dim3(NBLK), dim3(THREADS), 0, stream>>>(
        leaves, (const char*)d_ws, out);
}

// Round 12
// 39.936 us; speedup vs baseline: 9.1858x; 1.1315x over previous
//
#include <hip/hip_runtime.h>

// Problem constants
#define NSPLIT  100
#define MTREE   20
#define MAXLEAF 64
#define EMB     32
#define NTREES  2000
#define BATCH   4096
#define OUTW    (NSPLIT*EMB)            // 3200
#define TAB_F4  (NSPLIT*MTREE*MAXLEAF*8) // 1,024,000 float4 in f32 table
#define SPLIT_B 81920                   // bf16 table bytes per split
#define PASS_B  40960                   // bf16 bytes per 10-tree pass

#define THREADS 512
#define CHUNKS  32                      // batch-chunks per split
#define BPC     (BATCH/CHUNKS)          // 128 batches/block, 1 per 4-lane group
#define NBLK    (NSPLIT*CHUNKS)         // 3200

// v12 = LDS gather with the staging tax removed.
//  kernel 1 (unchanged v11): f32 table -> bf16 table in d_ws, ONCE (8.2 MB).
//  kernel 2: stage each 10-tree pass (40 KiB) via pure global_load_lds DMA
//    from the bf16 table -- no cvt, no VGPR round-trip, half the bytes of
//    v10's f32 staging (262 MB L2-resident total vs 524 MB). Gather via
//    ds_read_b128 (0.75 cyc/row vs global path's measured ~3.5 cyc/row --
//    v11 proved the TCP divergent-line floor is ~45us; LDS port floor ~13us).
//  Shape = v10's spill-proven one: 512 thr, 1 batch per 4-lane group, 40 KiB
//  STATIC LDS, __launch_bounds__(512,4) -> VGPR cap 64 (real tier), 4
//  blocks/CU co-resident to cover the 3 barriers/block.
__device__ __forceinline__ unsigned int pk_bf16(float a, float b) {
    unsigned int r;
    asm("v_cvt_pk_bf16_f32 %0, %1, %2" : "=v"(r) : "v"(a), "v"(b));
    return r;
}

__device__ __forceinline__ void stage_dma(const void* gsrc, void* lbase) {
    __builtin_amdgcn_global_load_lds(
        (const __attribute__((address_space(1))) void*)gsrc,
        (__attribute__((address_space(3))) void*)lbase, 16, 0, 0);
}

// ---- kernel 1: f32 table -> bf16 table (row-major layout preserved) ----
__global__ __launch_bounds__(256) void cvt_tab(
    const float4* __restrict__ src, uint2* __restrict__ dst)
{
    const int i0 = blockIdx.x * 1024 + threadIdx.x;
#pragma unroll
    for (int k = 0; k < 4; ++k) {
        const int i = i0 + k * 256;          // 1000 blocks x 1024 = exact
        const float4 v = src[i];
        dst[i] = make_uint2(pk_bf16(v.x, v.y), pk_bf16(v.z, v.w));
    }
}

// ---- kernel 2: LDS gather, DMA-staged bf16 passes ----
__global__ __launch_bounds__(THREADS, 4) void leaf2emb_v12(
    const int* __restrict__ leaves,     // [BATCH, NTREES]
    const char* __restrict__ tab,       // bf16 table in d_ws, row = 64 B
    float* __restrict__ out)            // [BATCH, OUTW]
{
    __shared__ char tl[PASS_B];         // 40 KiB: one 10-tree pass

    // XCD-chunked swizzle: 3200 = 8 x 400 -> a split's 32 chunk-blocks stay
    // on one XCD; its ~80 KB bf16 slice is L2-resident for the DMA staging.
    const int bid = blockIdx.x;
    const int wkr = (bid & 7) * (NBLK / 8) + (bid >> 3);
    const int s     = wkr >> 5;
    const int chunk = wkr & 31;

    const int tid  = threadIdx.x;
    const int l    = tid & 3;           // lane-in-group: dims [8l, 8l+8)
    const int g    = tid >> 2;          // group id = batch slot (128 groups)
    const int w    = tid >> 6;          // wave id (uniform)
    const int lane = tid & 63;

    const char* gtab = tab + (size_t)s * SPLIT_B;

    // DMA one 40 KiB pass: 5 x 16B per lane; LDS dest is wave-uniform base
    // (HW appends lane*16), global src is per-lane -- linear both sides.
#define STAGE(P) { \
        const char* gs_ = gtab + (P) * PASS_B + w * 1024 + lane * 16; \
        char* lb_ = tl + w * 1024; \
        _Pragma("unroll") \
        for (int k = 0; k < 5; ++k) \
            stage_dma(gs_ + k * 8192, lb_ + k * 8192); \
    }

    // ---- stage pass 0 (trees 0..9) + pass-0 leaves ----
    STAGE(0)
    const int b = chunk * BPC + g;
    const int* lv = leaves + (size_t)b * NTREES + s * MTREE;
    int4 L0 = *(const int4*)(lv);       // trees 0..3
    int4 L1 = *(const int4*)(lv + 4);   // trees 4..7
    int2 Lh = *(const int2*)(lv + 8);   // trees 8,9

    const char* tb = tl + l * 16;
    float4 a0 = {0,0,0,0}, a1 = {0,0,0,0};   // dims [8l..8l+4), [8l+4..8l+8)

#define RD(T, LEAF) (*(const uint4*)(tb + (T)*4096 + ((LEAF) << 6)))
#define UNACC(V) { \
    a0.x += __uint_as_float((V).x << 16); a0.y += __uint_as_float((V).x & 0xffff0000u); \
    a0.z += __uint_as_float((V).y << 16); a0.w += __uint_as_float((V).y & 0xffff0000u); \
    a1.x += __uint_as_float((V).z << 16); a1.y += __uint_as_float((V).z & 0xffff0000u); \
    a1.z += __uint_as_float((V).w << 16); a1.w += __uint_as_float((V).w & 0xffff0000u); }

    // 10 trees from the staged pass: 4+4+2 reads in flight (<=4 uint4 live).
#define GATHER10(LQ0, LQ1, LP) { \
        uint4 v0 = RD(0, (LQ0).x), v1 = RD(1, (LQ0).y), \
              v2 = RD(2, (LQ0).z), v3 = RD(3, (LQ0).w); \
        UNACC(v0) UNACC(v1) UNACC(v2) UNACC(v3) \
        v0 = RD(4, (LQ1).x); v1 = RD(5, (LQ1).y); \
        v2 = RD(6, (LQ1).z); v3 = RD(7, (LQ1).w); \
        UNACC(v0) UNACC(v1) UNACC(v2) UNACC(v3) \
        v0 = RD(8, (LP).x);  v1 = RD(9, (LP).y); \
        UNACC(v0) UNACC(v1) }

    __syncthreads();                    // DMA pass 0 drained
    GATHER10(L0, L1, Lh)
    // pass-1 leaves: issued after gather reads, latency hides under barrier
    Lh = *(const int2*)(lv + 10);       // trees 10,11 -> pass rows 0,1
    L0 = *(const int4*)(lv + 12);       // trees 12..15 -> rows 2..5
    L1 = *(const int4*)(lv + 16);       // trees 16..19 -> rows 6..9
    __syncthreads();                    // all pass-0 gathers done

    // ---- stage pass 1 (trees 10..19) ----
    STAGE(1)
    __syncthreads();                    // DMA pass 1 drained
    {
        uint4 v0 = RD(0, Lh.x), v1 = RD(1, Lh.y);
        UNACC(v0) UNACC(v1)
        v0 = RD(2, L0.x); v1 = RD(3, L0.y);
        uint4 v2 = RD(4, L0.z), v3 = RD(5, L0.w);
        UNACC(v0) UNACC(v1) UNACC(v2) UNACC(v3)
        v0 = RD(6, L1.x); v1 = RD(7, L1.y); v2 = RD(8, L1.z); v3 = RD(9, L1.w);
        UNACC(v0) UNACC(v1) UNACC(v2) UNACC(v3)
    }

#undef STAGE
#undef RD
#undef UNACC
#undef GATHER10

    // group's 4 lanes write 2 float4 each -> contiguous 128B per (b, s)
    float* ob = out + (size_t)b * OUTW + s * EMB + l * 8;
    *(float4*)(ob)     = a0;
    *(float4*)(ob + 4) = a1;
}

extern "C" void kernel_launch(void* const* d_in, const int* in_sizes, int n_in,
                              void* d_out, int out_size, void* d_ws, size_t ws_size,
                              hipStream_t stream) {
    const int* leaves  = (const int*)d_in[0];
    const float* embed = (const float*)d_in[1];
    float* out         = (float*)d_out;

    // d_ws: 8.2 MB bf16 table (fully rewritten every call -> deterministic).
    cvt_tab<<<dim3(TAB_F4 / 1024), dim3(256), 0, stream>>>(
        (const float4*)embed, (uint2*)d_ws);

    leaf2emb_v12<<<dim3(NBLK), dim3(THREADS), 0, stream>>>(
        leaves, (const char*)d_ws, out);
}